// Round 1
// baseline (626.740 us; speedup 1.0000x reference)
//
#include <hip/hip_runtime.h>
#include <stdint.h>

// ---------------------------------------------------------------------------
// CTBG circuit: 5 chained GEMMs, bf16 MFMA (16x16x32), m97-style 128x128 tile.
// Dims: B=16384; GEMM1: K=1536,N=1536; GEMM2: K=3072,N=1536;
//       GEMM3: K=1536,N=512 (relu); GEMM4: K=512,N=512 (relu); head: N=6.
// All dims divisible by tile sizes -> no bounds checks anywhere.
// ---------------------------------------------------------------------------

typedef __attribute__((ext_vector_type(8))) short short8;     // 8 bf16 bits
typedef __attribute__((ext_vector_type(4))) float floatx4;    // MFMA acc

typedef const __attribute__((address_space(1))) void* gas1_cvp;
typedef __attribute__((address_space(3))) void* gas3_vp;

__device__ __forceinline__ void load_lds16(const void* g, void* s) {
    // global -> LDS direct DMA, 16B/lane. LDS dst is wave-uniform base;
    // lane i lands at base + i*16 bytes.
    __builtin_amdgcn_global_load_lds((gas1_cvp)g, (gas3_vp)s, 16, 0, 0);
}

__device__ __forceinline__ unsigned short f2bf(float f) {
    unsigned int u = __float_as_uint(f);
    u = u + 0x7fffu + ((u >> 16) & 1u);          // RNE
    return (unsigned short)(u >> 16);
}
__device__ __forceinline__ float bf2f(unsigned short h) {
    return __uint_as_float(((unsigned int)h) << 16);
}

// ---------------------------------------------------------------------------
// x (fp32 [B][1536]) -> bf16 into xcat[:, 0:1536] (row stride 3072)
// ---------------------------------------------------------------------------
__global__ void convert_x_kernel(const float* __restrict__ x,
                                 unsigned short* __restrict__ xcat) {
    int idx = blockIdx.x * blockDim.x + threadIdx.x;   // over B*1536/4
    int e = idx * 4;
    int b = e / 1536;
    int j = e - b * 1536;
    float4 v = *(const float4*)(x + e);
    ushort4 o;
    o.x = f2bf(v.x); o.y = f2bf(v.y); o.z = f2bf(v.z); o.w = f2bf(v.w);
    *(ushort4*)(xcat + (size_t)b * 3072 + j) = o;
}

// ---------------------------------------------------------------------------
// Weight prep: out[n][k] = bf16( w[k][n] * (MASKED ? mask[n][k] : 1) )
// w: [K][N] fp32 row-major; mask: [N][K] fp32; out: [N][K] bf16.
// 64x64 tile transpose through LDS; all global accesses coalesced float4.
// ---------------------------------------------------------------------------
template <bool MASKED>
__global__ void prep_w_kernel(const float* __restrict__ w,
                              const float* __restrict__ mask,
                              unsigned short* __restrict__ out,
                              int K, int N) {
    __shared__ float tile[64][65];                 // [n_local][k_local], +1 pad
    int n0 = blockIdx.x * 64;
    int k0 = blockIdx.y * 64;
    int t = threadIdx.x;
    int c4 = (t & 15) * 4;                         // 0..60 step 4
    int r  = t >> 4;                               // 0..15

    #pragma unroll
    for (int p = 0; p < 4; ++p) {
        int kk = r + p * 16;
        float4 v = *(const float4*)(w + (size_t)(k0 + kk) * N + n0 + c4);
        tile[c4 + 0][kk] = v.x;
        tile[c4 + 1][kk] = v.y;
        tile[c4 + 2][kk] = v.z;
        tile[c4 + 3][kk] = v.w;
    }
    __syncthreads();
    #pragma unroll
    for (int p = 0; p < 4; ++p) {
        int nn = r + p * 16;
        float mx = 1.f, my = 1.f, mz = 1.f, mw = 1.f;
        if (MASKED) {
            float4 m = *(const float4*)(mask + (size_t)(n0 + nn) * K + k0 + c4);
            mx = m.x; my = m.y; mz = m.z; mw = m.w;
        }
        ushort4 o;
        o.x = f2bf(tile[nn][c4 + 0] * mx);
        o.y = f2bf(tile[nn][c4 + 1] * my);
        o.z = f2bf(tile[nn][c4 + 2] * mz);
        o.w = f2bf(tile[nn][c4 + 3] * mw);
        *(ushort4*)(out + (size_t)(n0 + nn) * K + k0 + c4) = o;
    }
}

// ---------------------------------------------------------------------------
// C[m][n] = sum_k A[m][k] * Bt[n][k] + bias[n]   (optional relu), bf16 out.
// Block: 256 thr = 4 waves (2x2), tile 128x128, BK=32, 16x16x32 bf16 MFMA.
// Staging: global_load_lds 16B/lane (2 issues per wave per operand).
// ---------------------------------------------------------------------------
template <bool RELU>
__global__ __launch_bounds__(256) void gemm_bt_kernel(
        const unsigned short* __restrict__ A,   // [M][lda] bf16
        const unsigned short* __restrict__ Bt,  // [N][K]  bf16
        const float* __restrict__ bias,         // [N]
        unsigned short* __restrict__ C,         // [M][ldc] bf16
        int K, int lda, int ldc) {
    __shared__ unsigned short As[128 * 32];     // [row][k] row-major
    __shared__ unsigned short Bs[128 * 32];     // [n_local][k]

    const int m0 = blockIdx.y * 128;
    const int n0 = blockIdx.x * 128;
    const int t    = threadIdx.x;
    const int lane = t & 63;
    const int w    = t >> 6;        // wave 0..3
    const int wm   = w >> 1;        // wave row  (0/1)
    const int wn   = w & 1;         // wave col  (0/1)
    const int lm   = lane & 15;
    const int lq   = lane >> 4;     // quad 0..3

    // staging: chunk c covers rows [c*16, c*16+16), lane -> (row=c*16+l/4, col=(l&3)*8)
    const int srow = lane >> 2;
    const int scol = (lane & 3) * 8;
    const unsigned short* ag0 = A  + (size_t)(m0 + w * 16 + srow) * lda + scol;
    const unsigned short* ag1 = A  + (size_t)(m0 + (4 + w) * 16 + srow) * lda + scol;
    const unsigned short* bg0 = Bt + (size_t)(n0 + w * 16 + srow) * K + scol;
    const unsigned short* bg1 = Bt + (size_t)(n0 + (4 + w) * 16 + srow) * K + scol;
    unsigned short* sA0 = As + w * 512;
    unsigned short* sA1 = As + (4 + w) * 512;
    unsigned short* sB0 = Bs + w * 512;
    unsigned short* sB1 = Bs + (4 + w) * 512;

    // fragment LDS read offsets (constant across K iters)
    const unsigned short* arp[4];
    const unsigned short* brp[4];
    #pragma unroll
    for (int i = 0; i < 4; ++i) {
        arp[i] = As + (wm * 64 + i * 16 + lm) * 32 + lq * 8;
        brp[i] = Bs + (wn * 64 + i * 16 + lm) * 32 + lq * 8;
    }

    floatx4 acc[4][4] = {};

    for (int k0 = 0; k0 < K; k0 += 32) {
        __syncthreads();                      // prev iter's ds_reads done
        load_lds16(ag0 + k0, sA0);
        load_lds16(ag1 + k0, sA1);
        load_lds16(bg0 + k0, sB0);
        load_lds16(bg1 + k0, sB1);
        __syncthreads();                      // drains vmcnt before barrier

        short8 af[4], bf8[4];
        #pragma unroll
        for (int i = 0; i < 4; ++i) {
            af[i]  = *(const short8*)arp[i];
            bf8[i] = *(const short8*)brp[i];
        }
        #pragma unroll
        for (int mi = 0; mi < 4; ++mi)
            #pragma unroll
            for (int ni = 0; ni < 4; ++ni)
                acc[mi][ni] = __builtin_amdgcn_mfma_f32_16x16x32_bf16(
                    af[mi], bf8[ni], acc[mi][ni], 0, 0, 0);
    }

    // epilogue: C/D layout col=lane&15, row=(lane>>4)*4+reg
    float bv[4];
    #pragma unroll
    for (int ni = 0; ni < 4; ++ni) bv[ni] = bias[n0 + wn * 64 + ni * 16 + lm];

    #pragma unroll
    for (int mi = 0; mi < 4; ++mi) {
        int rbase = m0 + wm * 64 + mi * 16 + lq * 4;
        #pragma unroll
        for (int ni = 0; ni < 4; ++ni) {
            int cc = n0 + wn * 64 + ni * 16 + lm;
            #pragma unroll
            for (int r = 0; r < 4; ++r) {
                float v = acc[mi][ni][r] + bv[ni];
                if (RELU) v = fmaxf(v, 0.f);
                C[(size_t)(rbase + r) * ldc + cc] = f2bf(v);
            }
        }
    }
}

// ---------------------------------------------------------------------------
// head: out[b][a] = relu( sum_k h[b][k]*w3[k][a] + b3[a] ), N=6 tiny.
// ---------------------------------------------------------------------------
__global__ void head_kernel(const unsigned short* __restrict__ h,  // [B][512]
                            const float* __restrict__ w3,          // [512][6]
                            const float* __restrict__ b3,          // [6]
                            float* __restrict__ out) {             // [B][6]
    int idx = blockIdx.x * blockDim.x + threadIdx.x;  // B*6
    int b = idx / 6;
    int a = idx - b * 6;
    const unsigned short* hp = h + (size_t)b * 512;
    float s = b3[a];
    #pragma unroll 4
    for (int k4 = 0; k4 < 512; k4 += 4) {
        ushort4 hv = *(const ushort4*)(hp + k4);
        s += bf2f(hv.x) * w3[(k4 + 0) * 6 + a];
        s += bf2f(hv.y) * w3[(k4 + 1) * 6 + a];
        s += bf2f(hv.z) * w3[(k4 + 2) * 6 + a];
        s += bf2f(hv.w) * w3[(k4 + 3) * 6 + a];
    }
    out[idx] = fmaxf(s, 0.f);
}

// ---------------------------------------------------------------------------
extern "C" void kernel_launch(void* const* d_in, const int* in_sizes, int n_in,
                              void* d_out, int out_size, void* d_ws, size_t ws_size,
                              hipStream_t stream) {
    const float* x        = (const float*)d_in[0];
    const float* gpe_mask = (const float*)d_in[1];
    const float* gpe_w    = (const float*)d_in[2];
    const float* gpe_b    = (const float*)d_in[3];
    const float* gpi_mask = (const float*)d_in[4];
    const float* gpi_w    = (const float*)d_in[5];
    const float* gpi_b    = (const float*)d_in[6];
    const float* w1       = (const float*)d_in[7];
    const float* b1       = (const float*)d_in[8];
    const float* w2       = (const float*)d_in[9];
    const float* b2       = (const float*)d_in[10];
    const float* w3       = (const float*)d_in[11];
    const float* b3       = (const float*)d_in[12];
    float* out = (float*)d_out;

    // workspace carve (bytes). Total 200,802,304.
    char* ws = (char*)d_ws;
    unsigned short* xcat   = (unsigned short*)(ws);              // B*3072 bf16
    unsigned short* gpiout = (unsigned short*)(ws + 100663296);  // B*1536
    unsigned short* h1     = (unsigned short*)(ws + 150994944);  // B*512
    unsigned short* h2     = (unsigned short*)(ws + 167772160);  // B*512
    unsigned short* wgpet  = (unsigned short*)(ws + 184549376);  // 1536*1536
    unsigned short* wgpit  = (unsigned short*)(ws + 189267968);  // 1536*3072
    unsigned short* w1t    = (unsigned short*)(ws + 198705152);  // 512*1536
    unsigned short* w2t    = (unsigned short*)(ws + 200278016);  // 512*512

    // ---- prep ----
    convert_x_kernel<<<dim3(16384 * 1536 / 4 / 256), dim3(256), 0, stream>>>(x, xcat);
    prep_w_kernel<true><<<dim3(1536 / 64, 1536 / 64), dim3(256), 0, stream>>>(
        gpe_w, gpe_mask, wgpet, 1536, 1536);
    prep_w_kernel<true><<<dim3(1536 / 64, 3072 / 64), dim3(256), 0, stream>>>(
        gpi_w, gpi_mask, wgpit, 3072, 1536);
    prep_w_kernel<false><<<dim3(512 / 64, 1536 / 64), dim3(256), 0, stream>>>(
        w1, nullptr, w1t, 1536, 512);
    prep_w_kernel<false><<<dim3(512 / 64, 512 / 64), dim3(256), 0, stream>>>(
        w2, nullptr, w2t, 512, 512);

    // ---- GEMM chain ----
    // gpe_out -> xcat[:, 1536:3072]  (concat for free)
    gemm_bt_kernel<false><<<dim3(12, 128), dim3(256), 0, stream>>>(
        xcat, wgpet, gpe_b, xcat + 1536, 1536, 3072, 3072);
    // gpi_out = [x|gpe_out] @ Wgpi + b
    gemm_bt_kernel<false><<<dim3(12, 128), dim3(256), 0, stream>>>(
        xcat, wgpit, gpi_b, gpiout, 3072, 3072, 1536);
    // h1 = relu(gpi_out @ w1 + b1)
    gemm_bt_kernel<true><<<dim3(4, 128), dim3(256), 0, stream>>>(
        gpiout, w1t, b1, h1, 1536, 1536, 512);
    // h2 = relu(h1 @ w2 + b2)
    gemm_bt_kernel<true><<<dim3(4, 128), dim3(256), 0, stream>>>(
        h1, w2t, b2, h2, 512, 512, 512);
    // out = relu(h2 @ w3 + b3)
    head_kernel<<<dim3(16384 * 6 / 256), dim3(256), 0, stream>>>(h2, w3, b3, out);
}

// Round 2
// 468.613 us; speedup vs baseline: 1.3374x; 1.3374x over previous
//
#include <hip/hip_runtime.h>
#include <stdint.h>

// ---------------------------------------------------------------------------
// CTBG circuit, round 2: algebraic collapse of the two (linear!) masked layers.
//   gpi_out = x @ (Wi_top_eff + We_eff @ Wi_bot_eff) + (gpe_b @ Wi_bot_eff + gpi_b)
// Chain: combine-GEMM 1536^3 (tiny) -> main GEMM 16384x1536x1536 ->
//        relu-GEMM 16384x512x1536 -> relu-GEMM 16384x512x512 -> head N=6.
// Total ~119 GF vs 266 GF in round 1.
// ---------------------------------------------------------------------------

typedef __attribute__((ext_vector_type(8))) short short8;     // 8 bf16 bits
typedef __attribute__((ext_vector_type(4))) float floatx4;    // MFMA acc

typedef const __attribute__((address_space(1))) void* gas1_cvp;
typedef __attribute__((address_space(3))) void* gas3_vp;

__device__ __forceinline__ void load_lds16(const void* g, void* s) {
    __builtin_amdgcn_global_load_lds((gas1_cvp)g, (gas3_vp)s, 16, 0, 0);
}

__device__ __forceinline__ unsigned short f2bf(float f) {
    unsigned int u = __float_as_uint(f);
    u = u + 0x7fffu + ((u >> 16) & 1u);          // RNE
    return (unsigned short)(u >> 16);
}
__device__ __forceinline__ float bf2f(unsigned short h) {
    return __uint_as_float(((unsigned int)h) << 16);
}

// ---------------------------------------------------------------------------
// x (fp32 [B][1536]) -> bf16 [B][1536] flat
// ---------------------------------------------------------------------------
__global__ void convert_x_kernel(const float* __restrict__ x,
                                 unsigned short* __restrict__ xb) {
    int idx = blockIdx.x * blockDim.x + threadIdx.x;   // over B*1536/4
    int e = idx * 4;
    float4 v = *(const float4*)(x + e);
    ushort4 o;
    o.x = f2bf(v.x); o.y = f2bf(v.y); o.z = f2bf(v.z); o.w = f2bf(v.w);
    *(ushort4*)(xb + e) = o;
}

// ---------------------------------------------------------------------------
// Transposing weight prep: out[n][k] = bf16( w[k][n] * (MASKED ? mask[n][k] : 1) )
// w row stride ldw, mask row stride ldm, out row stride ldo.
// grid.x over n/64, grid.y over k/64. 64x64 LDS tile transpose, all coalesced.
// ---------------------------------------------------------------------------
template <bool MASKED>
__global__ void prep_w_kernel(const float* __restrict__ w,
                              const float* __restrict__ mask,
                              unsigned short* __restrict__ out,
                              int ldw, int ldm, int ldo) {
    __shared__ float tile[64][65];                 // [n_local][k_local], +1 pad
    int n0 = blockIdx.x * 64;
    int k0 = blockIdx.y * 64;
    int t = threadIdx.x;
    int c4 = (t & 15) * 4;                         // 0..60 step 4
    int r  = t >> 4;                               // 0..15

    #pragma unroll
    for (int p = 0; p < 4; ++p) {
        int kk = r + p * 16;
        float4 v = *(const float4*)(w + (size_t)(k0 + kk) * ldw + n0 + c4);
        tile[c4 + 0][kk] = v.x;
        tile[c4 + 1][kk] = v.y;
        tile[c4 + 2][kk] = v.z;
        tile[c4 + 3][kk] = v.w;
    }
    __syncthreads();
    #pragma unroll
    for (int p = 0; p < 4; ++p) {
        int nn = r + p * 16;
        float mx = 1.f, my = 1.f, mz = 1.f, mw = 1.f;
        if (MASKED) {
            float4 m = *(const float4*)(mask + (size_t)(n0 + nn) * ldm + k0 + c4);
            mx = m.x; my = m.y; mz = m.z; mw = m.w;
        }
        ushort4 o;
        o.x = f2bf(tile[nn][c4 + 0] * mx);
        o.y = f2bf(tile[nn][c4 + 1] * my);
        o.z = f2bf(tile[nn][c4 + 2] * mz);
        o.w = f2bf(tile[nn][c4 + 3] * mw);
        *(ushort4*)(out + (size_t)(n0 + nn) * ldo + k0 + c4) = o;
    }
}

// ---------------------------------------------------------------------------
// Non-transposing masked prep: out[i][j] = bf16( w[i][j] * mask[j][i] )
// (mask is read transposed through an LDS tile). grid.x over j, grid.y over i.
// ---------------------------------------------------------------------------
__global__ void prep_w_nt_kernel(const float* __restrict__ w,
                                 const float* __restrict__ mask,
                                 unsigned short* __restrict__ out,
                                 int ldw, int ldm, int ldo) {
    __shared__ float tm[64][65];                   // [i_local][j_local]
    int j0 = blockIdx.x * 64;
    int i0 = blockIdx.y * 64;
    int t = threadIdx.x;
    int c4 = (t & 15) * 4;
    int r  = t >> 4;

    #pragma unroll
    for (int p = 0; p < 4; ++p) {
        int jj = r + p * 16;
        float4 m = *(const float4*)(mask + (size_t)(j0 + jj) * ldm + i0 + c4);
        tm[c4 + 0][jj] = m.x;
        tm[c4 + 1][jj] = m.y;
        tm[c4 + 2][jj] = m.z;
        tm[c4 + 3][jj] = m.w;
    }
    __syncthreads();
    #pragma unroll
    for (int p = 0; p < 4; ++p) {
        int ii = r + p * 16;
        float4 v = *(const float4*)(w + (size_t)(i0 + ii) * ldw + j0 + c4);
        ushort4 o;
        o.x = f2bf(v.x * tm[ii][c4 + 0]);
        o.y = f2bf(v.y * tm[ii][c4 + 1]);
        o.z = f2bf(v.z * tm[ii][c4 + 2]);
        o.w = f2bf(v.w * tm[ii][c4 + 3]);
        *(ushort4*)(out + (size_t)(i0 + ii) * ldo + j0 + c4) = o;
    }
}

// ---------------------------------------------------------------------------
// b_comb[u] = gpi_b[u] + sum_j gpe_b[j] * Wi_bot_t[u][j]   (one wave per u)
// ---------------------------------------------------------------------------
__global__ void bcomb_kernel(const float* __restrict__ gpe_b,
                             const float* __restrict__ gpi_b,
                             const unsigned short* __restrict__ wbt,  // [1536][1536]
                             float* __restrict__ bcomb) {
    int u = blockIdx.x * 4 + (threadIdx.x >> 6);
    int lane = threadIdx.x & 63;
    const unsigned short* row = wbt + (size_t)u * 1536;
    float s = 0.f;
    for (int j = lane; j < 1536; j += 64) s += gpe_b[j] * bf2f(row[j]);
    #pragma unroll
    for (int off = 32; off; off >>= 1) s += __shfl_down(s, off, 64);
    if (lane == 0) bcomb[u] = gpi_b[u] + s;
}

// ---------------------------------------------------------------------------
// C[m][n] = sum_k A[m][k]*Bt[n][k] + (ADDMAT ? Add[m][n] : bias[n]), opt relu.
// Block: 256 thr = 4 waves (2x2), tile 128x128, BK=32, 16x16x32 bf16 MFMA.
// ---------------------------------------------------------------------------
template <bool RELU, bool ADDMAT>
__global__ __launch_bounds__(256) void gemm_bt_kernel(
        const unsigned short* __restrict__ A,    // [M][lda] bf16
        const unsigned short* __restrict__ Bt,   // [N][K]  bf16
        const float* __restrict__ bias,          // [N]  (unused if ADDMAT)
        const unsigned short* __restrict__ Add,  // [M][ldc] bf16 (if ADDMAT)
        unsigned short* __restrict__ C,          // [M][ldc] bf16
        int K, int lda, int ldc) {
    __shared__ unsigned short As[128 * 32];
    __shared__ unsigned short Bs[128 * 32];

    const int m0 = blockIdx.y * 128;
    const int n0 = blockIdx.x * 128;
    const int t    = threadIdx.x;
    const int lane = t & 63;
    const int w    = t >> 6;
    const int wm   = w >> 1;
    const int wn   = w & 1;
    const int lm   = lane & 15;
    const int lq   = lane >> 4;

    const int srow = lane >> 2;
    const int scol = (lane & 3) * 8;
    const unsigned short* ag0 = A  + (size_t)(m0 + w * 16 + srow) * lda + scol;
    const unsigned short* ag1 = A  + (size_t)(m0 + (4 + w) * 16 + srow) * lda + scol;
    const unsigned short* bg0 = Bt + (size_t)(n0 + w * 16 + srow) * K + scol;
    const unsigned short* bg1 = Bt + (size_t)(n0 + (4 + w) * 16 + srow) * K + scol;
    unsigned short* sA0 = As + w * 512;
    unsigned short* sA1 = As + (4 + w) * 512;
    unsigned short* sB0 = Bs + w * 512;
    unsigned short* sB1 = Bs + (4 + w) * 512;

    const unsigned short* arp[4];
    const unsigned short* brp[4];
    #pragma unroll
    for (int i = 0; i < 4; ++i) {
        arp[i] = As + (wm * 64 + i * 16 + lm) * 32 + lq * 8;
        brp[i] = Bs + (wn * 64 + i * 16 + lm) * 32 + lq * 8;
    }

    floatx4 acc[4][4] = {};

    for (int k0 = 0; k0 < K; k0 += 32) {
        __syncthreads();
        load_lds16(ag0 + k0, sA0);
        load_lds16(ag1 + k0, sA1);
        load_lds16(bg0 + k0, sB0);
        load_lds16(bg1 + k0, sB1);
        __syncthreads();

        short8 af[4], bf8[4];
        #pragma unroll
        for (int i = 0; i < 4; ++i) {
            af[i]  = *(const short8*)arp[i];
            bf8[i] = *(const short8*)brp[i];
        }
        #pragma unroll
        for (int mi = 0; mi < 4; ++mi)
            #pragma unroll
            for (int ni = 0; ni < 4; ++ni)
                acc[mi][ni] = __builtin_amdgcn_mfma_f32_16x16x32_bf16(
                    af[mi], bf8[ni], acc[mi][ni], 0, 0, 0);
    }

    // epilogue: C/D layout col=lane&15, row=(lane>>4)*4+reg
    float bv[4] = {0.f, 0.f, 0.f, 0.f};
    if (!ADDMAT) {
        #pragma unroll
        for (int ni = 0; ni < 4; ++ni) bv[ni] = bias[n0 + wn * 64 + ni * 16 + lm];
    }

    #pragma unroll
    for (int mi = 0; mi < 4; ++mi) {
        int rbase = m0 + wm * 64 + mi * 16 + lq * 4;
        #pragma unroll
        for (int ni = 0; ni < 4; ++ni) {
            int cc = n0 + wn * 64 + ni * 16 + lm;
            #pragma unroll
            for (int r = 0; r < 4; ++r) {
                float v = acc[mi][ni][r];
                if (ADDMAT) v += bf2f(Add[(size_t)(rbase + r) * ldc + cc]);
                else        v += bv[ni];
                if (RELU) v = fmaxf(v, 0.f);
                C[(size_t)(rbase + r) * ldc + cc] = f2bf(v);
            }
        }
    }
}

// ---------------------------------------------------------------------------
// head: out[b][a] = relu( sum_k h[b][k]*w3[k][a] + b3[a] ), N=6 tiny.
// ---------------------------------------------------------------------------
__global__ void head_kernel(const unsigned short* __restrict__ h,  // [B][512]
                            const float* __restrict__ w3,          // [512][6]
                            const float* __restrict__ b3,          // [6]
                            float* __restrict__ out) {             // [B][6]
    int idx = blockIdx.x * blockDim.x + threadIdx.x;  // B*6
    int b = idx / 6;
    int a = idx - b * 6;
    const unsigned short* hp = h + (size_t)b * 512;
    float s = b3[a];
    #pragma unroll 4
    for (int k4 = 0; k4 < 512; k4 += 4) {
        ushort4 hv = *(const ushort4*)(hp + k4);
        s += bf2f(hv.x) * w3[(k4 + 0) * 6 + a];
        s += bf2f(hv.y) * w3[(k4 + 1) * 6 + a];
        s += bf2f(hv.z) * w3[(k4 + 2) * 6 + a];
        s += bf2f(hv.w) * w3[(k4 + 3) * 6 + a];
    }
    out[idx] = fmaxf(s, 0.f);
}

// ---------------------------------------------------------------------------
extern "C" void kernel_launch(void* const* d_in, const int* in_sizes, int n_in,
                              void* d_out, int out_size, void* d_ws, size_t ws_size,
                              hipStream_t stream) {
    const float* x        = (const float*)d_in[0];
    const float* gpe_mask = (const float*)d_in[1];
    const float* gpe_w    = (const float*)d_in[2];
    const float* gpe_b    = (const float*)d_in[3];
    const float* gpi_mask = (const float*)d_in[4];
    const float* gpi_w    = (const float*)d_in[5];
    const float* gpi_b    = (const float*)d_in[6];
    const float* w1       = (const float*)d_in[7];
    const float* b1       = (const float*)d_in[8];
    const float* w2       = (const float*)d_in[9];
    const float* b2       = (const float*)d_in[10];
    const float* w3       = (const float*)d_in[11];
    const float* b3       = (const float*)d_in[12];
    float* out = (float*)d_out;

    // workspace carve (bytes), total ~155.2 MB
    char* ws = (char*)d_ws;
    unsigned short* xb      = (unsigned short*)(ws);              // B*1536 bf16
    unsigned short* gpiout  = (unsigned short*)(ws + 50331648);   // B*1536
    unsigned short* h1      = (unsigned short*)(ws + 100663296);  // B*512
    unsigned short* h2      = (unsigned short*)(ws + 117440512);  // B*512
    unsigned short* wi_top  = (unsigned short*)(ws + 134217728);  // [u][i] 1536^2
    unsigned short* wi_bot  = (unsigned short*)(ws + 138936320);  // [u][j] 1536^2
    unsigned short* we_nt   = (unsigned short*)(ws + 143654912);  // [i][j] 1536^2
    unsigned short* wct     = (unsigned short*)(ws + 148373504);  // [u][i] 1536^2
    unsigned short* w1t     = (unsigned short*)(ws + 153092096);  // [n][k] 512x1536
    unsigned short* w2t     = (unsigned short*)(ws + 154664960);  // [n][k] 512x512
    float*          bcomb   = (float*)(ws + 155189248);           // [1536]

    // ---- prep ----
    convert_x_kernel<<<dim3(16384 * 1536 / 4 / 256), dim3(256), 0, stream>>>(x, xb);
    // Wi_top_t[u][i] = gpi_w[i][u]*gpi_mask[u][i], i in [0,1536)
    prep_w_kernel<true><<<dim3(24, 24), dim3(256), 0, stream>>>(
        gpi_w, gpi_mask, wi_top, 1536, 3072, 1536);
    // Wi_bot_t[u][j] = gpi_w[1536+j][u]*gpi_mask[u][1536+j]
    prep_w_kernel<true><<<dim3(24, 24), dim3(256), 0, stream>>>(
        gpi_w + (size_t)1536 * 1536, gpi_mask + 1536, wi_bot, 1536, 3072, 1536);
    // We_nt[i][j] = gpe_w[i][j]*gpe_mask[j][i]
    prep_w_nt_kernel<<<dim3(24, 24), dim3(256), 0, stream>>>(
        gpe_w, gpe_mask, we_nt, 1536, 1536, 1536);
    // w1t[n][k], w2t[n][k]
    prep_w_kernel<false><<<dim3(8, 24), dim3(256), 0, stream>>>(
        w1, nullptr, w1t, 512, 0, 1536);
    prep_w_kernel<false><<<dim3(8, 8), dim3(256), 0, stream>>>(
        w2, nullptr, w2t, 512, 0, 512);
    // bias fold: bcomb = gpi_b + gpe_b @ Wi_bot_eff
    bcomb_kernel<<<dim3(384), dim3(256), 0, stream>>>(gpe_b, gpi_b, wi_bot, bcomb);

    // ---- GEMM chain ----
    // combine: Wct[u][i] = sum_j Wi_bot_t[u][j]*We_nt[i][j] + Wi_top_t[u][i]
    gemm_bt_kernel<false, true><<<dim3(12, 12), dim3(256), 0, stream>>>(
        wi_bot, we_nt, nullptr, wi_top, wct, 1536, 1536, 1536);
    // main: gpi_out = x @ Wc + bcomb
    gemm_bt_kernel<false, false><<<dim3(12, 128), dim3(256), 0, stream>>>(
        xb, wct, bcomb, nullptr, gpiout, 1536, 1536, 1536);
    // h1 = relu(gpi_out @ w1 + b1)
    gemm_bt_kernel<true, false><<<dim3(4, 128), dim3(256), 0, stream>>>(
        gpiout, w1t, b1, nullptr, h1, 1536, 1536, 512);
    // h2 = relu(h1 @ w2 + b2)
    gemm_bt_kernel<true, false><<<dim3(4, 128), dim3(256), 0, stream>>>(
        h1, w2t, b2, nullptr, h2, 512, 512, 512);
    // out = relu(h2 @ w3 + b3)
    head_kernel<<<dim3(16384 * 6 / 256), dim3(256), 0, stream>>>(h2, w3, b3, out);
}

// Round 3
// 391.352 us; speedup vs baseline: 1.6015x; 1.1974x over previous
//
#include <hip/hip_runtime.h>
#include <stdint.h>

// ---------------------------------------------------------------------------
// CTBG circuit, round 3: full linear-chain collapse.
//   Wc[i,u]  = WiTop_eff[i,u] + sum_j We_eff[i,j] * WiBot_eff[j,u]   (1536^3)
//   W1c[i,n] = sum_u Wc[i,u] * w1[u,n]                                (1536x512x1536)
//   b1c[n]   = (gpi_b + gpe_b @ WiBot_eff) @ w1 + b1
//   h1 = relu(x @ W1c + b1c)        16384x512x1536  (25.8 GF)
//   h2 = relu(h1 @ w2 + b2)         16384x512x512   ( 8.6 GF)
//   out = relu(h2 @ w3 + b3)        N=6 head
// Batch FLOPs 34.5 GF vs 119 GF in round 2.
// ---------------------------------------------------------------------------

typedef __attribute__((ext_vector_type(8))) short short8;     // 8 bf16 bits
typedef __attribute__((ext_vector_type(4))) float floatx4;    // MFMA acc

typedef const __attribute__((address_space(1))) void* gas1_cvp;
typedef __attribute__((address_space(3))) void* gas3_vp;

__device__ __forceinline__ void load_lds16(const void* g, void* s) {
    __builtin_amdgcn_global_load_lds((gas1_cvp)g, (gas3_vp)s, 16, 0, 0);
}

__device__ __forceinline__ unsigned short f2bf(float f) {
    unsigned int u = __float_as_uint(f);
    u = u + 0x7fffu + ((u >> 16) & 1u);          // RNE
    return (unsigned short)(u >> 16);
}
__device__ __forceinline__ float bf2f(unsigned short h) {
    return __uint_as_float(((unsigned int)h) << 16);
}

// ---------------------------------------------------------------------------
__global__ void convert_x_kernel(const float* __restrict__ x,
                                 unsigned short* __restrict__ xb) {
    int idx = blockIdx.x * blockDim.x + threadIdx.x;   // over B*1536/4
    int e = idx * 4;
    float4 v = *(const float4*)(x + e);
    ushort4 o;
    o.x = f2bf(v.x); o.y = f2bf(v.y); o.z = f2bf(v.z); o.w = f2bf(v.w);
    *(ushort4*)(xb + e) = o;
}

__global__ void zero_kernel(float* __restrict__ p) {
    p[blockIdx.x * blockDim.x + threadIdx.x] = 0.f;
}

// ---------------------------------------------------------------------------
// Transposing weight prep: out[n][k] = bf16( w[k][n] * (MASKED ? mask[n][k] : 1) )
// ---------------------------------------------------------------------------
template <bool MASKED>
__global__ void prep_w_kernel(const float* __restrict__ w,
                              const float* __restrict__ mask,
                              unsigned short* __restrict__ out,
                              int ldw, int ldm, int ldo) {
    __shared__ float tile[64][65];
    int n0 = blockIdx.x * 64;
    int k0 = blockIdx.y * 64;
    int t = threadIdx.x;
    int c4 = (t & 15) * 4;
    int r  = t >> 4;

    #pragma unroll
    for (int p = 0; p < 4; ++p) {
        int kk = r + p * 16;
        float4 v = *(const float4*)(w + (size_t)(k0 + kk) * ldw + n0 + c4);
        tile[c4 + 0][kk] = v.x;
        tile[c4 + 1][kk] = v.y;
        tile[c4 + 2][kk] = v.z;
        tile[c4 + 3][kk] = v.w;
    }
    __syncthreads();
    #pragma unroll
    for (int p = 0; p < 4; ++p) {
        int nn = r + p * 16;
        float mx = 1.f, my = 1.f, mz = 1.f, mw = 1.f;
        if (MASKED) {
            float4 m = *(const float4*)(mask + (size_t)(n0 + nn) * ldm + k0 + c4);
            mx = m.x; my = m.y; mz = m.z; mw = m.w;
        }
        ushort4 o;
        o.x = f2bf(tile[nn][c4 + 0] * mx);
        o.y = f2bf(tile[nn][c4 + 1] * my);
        o.z = f2bf(tile[nn][c4 + 2] * mz);
        o.w = f2bf(tile[nn][c4 + 3] * mw);
        *(ushort4*)(out + (size_t)(n0 + nn) * ldo + k0 + c4) = o;
    }
}

// ---------------------------------------------------------------------------
// Non-transposing masked prep: out[i][j] = bf16( w[i][j] * mask[j][i] )
// ---------------------------------------------------------------------------
__global__ void prep_w_nt_kernel(const float* __restrict__ w,
                                 const float* __restrict__ mask,
                                 unsigned short* __restrict__ out,
                                 int ldw, int ldm, int ldo) {
    __shared__ float tm[64][65];
    int j0 = blockIdx.x * 64;
    int i0 = blockIdx.y * 64;
    int t = threadIdx.x;
    int c4 = (t & 15) * 4;
    int r  = t >> 4;

    #pragma unroll
    for (int p = 0; p < 4; ++p) {
        int jj = r + p * 16;
        float4 m = *(const float4*)(mask + (size_t)(j0 + jj) * ldm + i0 + c4);
        tm[c4 + 0][jj] = m.x;
        tm[c4 + 1][jj] = m.y;
        tm[c4 + 2][jj] = m.z;
        tm[c4 + 3][jj] = m.w;
    }
    __syncthreads();
    #pragma unroll
    for (int p = 0; p < 4; ++p) {
        int ii = r + p * 16;
        float4 v = *(const float4*)(w + (size_t)(i0 + ii) * ldw + j0 + c4);
        ushort4 o;
        o.x = f2bf(v.x * tm[ii][c4 + 0]);
        o.y = f2bf(v.y * tm[ii][c4 + 1]);
        o.z = f2bf(v.z * tm[ii][c4 + 2]);
        o.w = f2bf(v.w * tm[ii][c4 + 3]);
        *(ushort4*)(out + (size_t)(i0 + ii) * ldo + j0 + c4) = o;
    }
}

// ---------------------------------------------------------------------------
// outv[u] = base[u] + sum_j avec[j] * wbt[u][j]   (one wave per u)
// ---------------------------------------------------------------------------
__global__ void bvec_kernel(const float* __restrict__ avec,
                            const float* __restrict__ base,
                            const unsigned short* __restrict__ wbt,
                            float* __restrict__ outv, int K, int ld) {
    int u = blockIdx.x * 4 + (threadIdx.x >> 6);
    int lane = threadIdx.x & 63;
    const unsigned short* rowp = wbt + (size_t)u * ld;
    float s = 0.f;
    for (int j = lane; j < K; j += 64) s += avec[j] * bf2f(rowp[j]);
    #pragma unroll
    for (int off = 32; off; off >>= 1) s += __shfl_down(s, off, 64);
    if (lane == 0) outv[u] = base[u] + s;
}

// ---------------------------------------------------------------------------
// C[m][n] = sum_k A[m][k]*Bt[n][k] + (ADDMAT ? Add[m][n] : bias[n]), opt relu.
// ---------------------------------------------------------------------------
template <bool RELU, bool ADDMAT>
__global__ __launch_bounds__(256) void gemm_bt_kernel(
        const unsigned short* __restrict__ A,
        const unsigned short* __restrict__ Bt,
        const float* __restrict__ bias,
        const unsigned short* __restrict__ Add,
        unsigned short* __restrict__ C,
        int K, int lda, int ldc) {
    __shared__ unsigned short As[128 * 32];
    __shared__ unsigned short Bs[128 * 32];

    const int m0 = blockIdx.y * 128;
    const int n0 = blockIdx.x * 128;
    const int t    = threadIdx.x;
    const int lane = t & 63;
    const int w    = t >> 6;
    const int wm   = w >> 1;
    const int wn   = w & 1;
    const int lm   = lane & 15;
    const int lq   = lane >> 4;

    const int srow = lane >> 2;
    const int scol = (lane & 3) * 8;
    const unsigned short* ag0 = A  + (size_t)(m0 + w * 16 + srow) * lda + scol;
    const unsigned short* ag1 = A  + (size_t)(m0 + (4 + w) * 16 + srow) * lda + scol;
    const unsigned short* bg0 = Bt + (size_t)(n0 + w * 16 + srow) * K + scol;
    const unsigned short* bg1 = Bt + (size_t)(n0 + (4 + w) * 16 + srow) * K + scol;
    unsigned short* sA0 = As + w * 512;
    unsigned short* sA1 = As + (4 + w) * 512;
    unsigned short* sB0 = Bs + w * 512;
    unsigned short* sB1 = Bs + (4 + w) * 512;

    const unsigned short* arp[4];
    const unsigned short* brp[4];
    #pragma unroll
    for (int i = 0; i < 4; ++i) {
        arp[i] = As + (wm * 64 + i * 16 + lm) * 32 + lq * 8;
        brp[i] = Bs + (wn * 64 + i * 16 + lm) * 32 + lq * 8;
    }

    floatx4 acc[4][4] = {};

    for (int k0 = 0; k0 < K; k0 += 32) {
        __syncthreads();
        load_lds16(ag0 + k0, sA0);
        load_lds16(ag1 + k0, sA1);
        load_lds16(bg0 + k0, sB0);
        load_lds16(bg1 + k0, sB1);
        __syncthreads();

        short8 af[4], bf8[4];
        #pragma unroll
        for (int i = 0; i < 4; ++i) {
            af[i]  = *(const short8*)arp[i];
            bf8[i] = *(const short8*)brp[i];
        }
        #pragma unroll
        for (int mi = 0; mi < 4; ++mi)
            #pragma unroll
            for (int ni = 0; ni < 4; ++ni)
                acc[mi][ni] = __builtin_amdgcn_mfma_f32_16x16x32_bf16(
                    af[mi], bf8[ni], acc[mi][ni], 0, 0, 0);
    }

    float bv[4] = {0.f, 0.f, 0.f, 0.f};
    if (!ADDMAT) {
        #pragma unroll
        for (int ni = 0; ni < 4; ++ni) bv[ni] = bias[n0 + wn * 64 + ni * 16 + lm];
    }

    #pragma unroll
    for (int mi = 0; mi < 4; ++mi) {
        int rbase = m0 + wm * 64 + mi * 16 + lq * 4;
        #pragma unroll
        for (int ni = 0; ni < 4; ++ni) {
            int cc = n0 + wn * 64 + ni * 16 + lm;
            #pragma unroll
            for (int r = 0; r < 4; ++r) {
                float v = acc[mi][ni][r];
                if (ADDMAT) v += bf2f(Add[(size_t)(rbase + r) * ldc + cc]);
                else        v += bv[ni];
                if (RELU) v = fmaxf(v, 0.f);
                C[(size_t)(rbase + r) * ldc + cc] = f2bf(v);
            }
        }
    }
}

// ---------------------------------------------------------------------------
// head: one wave per row, coalesced 16B/lane, shuffle-reduce 6 sums.
// ---------------------------------------------------------------------------
__global__ void head_kernel(const unsigned short* __restrict__ h,
                            const float* __restrict__ w3,
                            const float* __restrict__ b3,
                            float* __restrict__ out) {
    int row = blockIdx.x * 4 + (threadIdx.x >> 6);
    int lane = threadIdx.x & 63;
    const unsigned short* hp = h + (size_t)row * 512 + lane * 8;
    ushort4 ha = *(const ushort4*)(hp);
    ushort4 hb = *(const ushort4*)(hp + 4);
    float hv[8] = {bf2f(ha.x), bf2f(ha.y), bf2f(ha.z), bf2f(ha.w),
                   bf2f(hb.x), bf2f(hb.y), bf2f(hb.z), bf2f(hb.w)};
    const float* wp = w3 + lane * 48;
    float s[6] = {0.f, 0.f, 0.f, 0.f, 0.f, 0.f};
    #pragma unroll
    for (int j = 0; j < 8; ++j)
        #pragma unroll
        for (int a = 0; a < 6; ++a)
            s[a] += hv[j] * wp[j * 6 + a];
    #pragma unroll
    for (int a = 0; a < 6; ++a)
        #pragma unroll
        for (int off = 32; off; off >>= 1)
            s[a] += __shfl_down(s[a], off, 64);
    if (lane == 0) {
        #pragma unroll
        for (int a = 0; a < 6; ++a)
            out[(size_t)row * 6 + a] = fmaxf(s[a] + b3[a], 0.f);
    }
}

// ---------------------------------------------------------------------------
extern "C" void kernel_launch(void* const* d_in, const int* in_sizes, int n_in,
                              void* d_out, int out_size, void* d_ws, size_t ws_size,
                              hipStream_t stream) {
    const float* x        = (const float*)d_in[0];
    const float* gpe_mask = (const float*)d_in[1];
    const float* gpe_w    = (const float*)d_in[2];
    const float* gpe_b    = (const float*)d_in[3];
    const float* gpi_mask = (const float*)d_in[4];
    const float* gpi_w    = (const float*)d_in[5];
    const float* gpi_b    = (const float*)d_in[6];
    const float* w1       = (const float*)d_in[7];
    const float* b1       = (const float*)d_in[8];
    const float* w2       = (const float*)d_in[9];
    const float* b2       = (const float*)d_in[10];
    const float* w3       = (const float*)d_in[11];
    const float* b3       = (const float*)d_in[12];
    float* out = (float*)d_out;

    // workspace carve (bytes), total ~106.5 MB
    char* ws = (char*)d_ws;
    unsigned short* xb        = (unsigned short*)(ws);              // B*1536 bf16
    unsigned short* h1        = (unsigned short*)(ws + 50331648);   // B*512
    unsigned short* h2        = (unsigned short*)(ws + 67108864);   // B*512
    unsigned short* wi_topnt  = (unsigned short*)(ws + 83886080);   // [i][u] 1536^2
    unsigned short* wi_bot    = (unsigned short*)(ws + 88604672);   // [u][j] 1536^2
    unsigned short* we_nt     = (unsigned short*)(ws + 93323264);   // [i][j] 1536^2
    unsigned short* wc_nt     = (unsigned short*)(ws + 98041856);   // [i][u] 1536^2
    unsigned short* w1t       = (unsigned short*)(ws + 102760448);  // [n][u] 512x1536
    unsigned short* w2t       = (unsigned short*)(ws + 104333312);  // [n][k] 512x512
    unsigned short* w1ct      = (unsigned short*)(ws + 104857600);  // [n][i] 512x1536
    float*          bc        = (float*)(ws + 106430464);           // [1536]
    float*          b1c       = (float*)(ws + 106436608);           // [512]
    float*          zvec      = (float*)(ws + 106438656);           // [1536] zeros

    // ---- prep ----
    convert_x_kernel<<<dim3(16384 * 1536 / 4 / 256), dim3(256), 0, stream>>>(x, xb);
    zero_kernel<<<dim3(6), dim3(256), 0, stream>>>(zvec);
    // wi_topnt[i][u] = gpi_w[i][u] * gpi_mask[u][i]
    prep_w_nt_kernel<<<dim3(24, 24), dim3(256), 0, stream>>>(
        gpi_w, gpi_mask, wi_topnt, 1536, 3072, 1536);
    // wi_bot[u][j] = gpi_w[1536+j][u] * gpi_mask[u][1536+j]
    prep_w_kernel<true><<<dim3(24, 24), dim3(256), 0, stream>>>(
        gpi_w + (size_t)1536 * 1536, gpi_mask + 1536, wi_bot, 1536, 3072, 1536);
    // we_nt[i][j] = gpe_w[i][j] * gpe_mask[j][i]
    prep_w_nt_kernel<<<dim3(24, 24), dim3(256), 0, stream>>>(
        gpe_w, gpe_mask, we_nt, 1536, 1536, 1536);
    // w1t[n][u] = w1[u][n];  w2t[n][k] = w2[k][n]
    prep_w_kernel<false><<<dim3(8, 24), dim3(256), 0, stream>>>(
        w1, nullptr, w1t, 512, 0, 1536);
    prep_w_kernel<false><<<dim3(8, 8), dim3(256), 0, stream>>>(
        w2, nullptr, w2t, 512, 0, 512);
    // bc[u] = gpi_b[u] + sum_j gpe_b[j]*wi_bot[u][j]
    bvec_kernel<<<dim3(384), dim3(256), 0, stream>>>(gpe_b, gpi_b, wi_bot, bc, 1536, 1536);
    // b1c[n] = b1[n] + sum_u bc[u]*w1t[n][u]
    bvec_kernel<<<dim3(128), dim3(256), 0, stream>>>(bc, b1, w1t, b1c, 1536, 1536);

    // ---- weight-combine GEMMs (tiny) ----
    // wc_nt[i][u] = sum_j we_nt[i][j]*wi_bot[u][j] + wi_topnt[i][u]
    gemm_bt_kernel<false, true><<<dim3(12, 12), dim3(256), 0, stream>>>(
        we_nt, wi_bot, nullptr, wi_topnt, wc_nt, 1536, 1536, 1536);
    // w1ct[n][i] = sum_u w1t[n][u]*wc_nt[i][u]   (zero bias)
    gemm_bt_kernel<false, false><<<dim3(12, 4), dim3(256), 0, stream>>>(
        w1t, wc_nt, zvec, nullptr, w1ct, 1536, 1536, 1536);

    // ---- batch GEMM chain ----
    // h1 = relu(xb @ W1c + b1c)
    gemm_bt_kernel<true, false><<<dim3(4, 128), dim3(256), 0, stream>>>(
        xb, w1ct, b1c, nullptr, h1, 1536, 1536, 512);
    // h2 = relu(h1 @ w2 + b2)
    gemm_bt_kernel<true, false><<<dim3(4, 128), dim3(256), 0, stream>>>(
        h1, w2t, b2, nullptr, h2, 512, 512, 512);
    // out = relu(h2 @ w3 + b3)
    head_kernel<<<dim3(16384 / 4), dim3(256), 0, stream>>>(h2, w3, b3, out);
}